// Round 9
// baseline (595.809 us; speedup 1.0000x reference)
//
#include <hip/hip_runtime.h>
#include <math.h>

#define N_NODES 50000
#define N_EDGES 800000
#define EP (N_EDGES + N_NODES)   // 850000 edges incl. self-loops
#define D 256
#define SLOPE 0.2f
#define CAP 64                   // per-dst bucket capacity; max degree ~45 << 64
#define SCATG 3321               // scatter blocks = ceil(EP/256)
#define TWG 512                  // transW blocks
#define CASTG 12500              // x-cast blocks (N*D/4 float4s / 256)

typedef __attribute__((ext_vector_type(8))) short short8;
typedef __attribute__((ext_vector_type(4))) float f32x4;
typedef const __attribute__((address_space(1))) unsigned int* as1_u32;
typedef __attribute__((address_space(3))) unsigned int* as3_u32;

__device__ __forceinline__ unsigned short f2b(float f) {
    unsigned u = __float_as_uint(f);
    unsigned r = (u + 0x7FFFu + ((u >> 16) & 1u)) >> 16;   // RNE
    return (unsigned short)r;
}
__device__ __forceinline__ float uas(unsigned u) { return __uint_as_float(u); }
__device__ __forceinline__ void g2lds16(const void* g, void* l) {
    __builtin_amdgcn_global_load_lds((as1_u32)g, (as3_u32)l, 16, 0, 0);
}

// ---------------- prep: bucket scatter FIRST (latency-bound), then transW + x cast (BW) ------------

__global__ __launch_bounds__(256) void prep(const int* __restrict__ ei,
                                            const float* __restrict__ W1,
                                            const float* __restrict__ W2,
                                            const float* __restrict__ x,
                                            unsigned short* __restrict__ Wt1,
                                            unsigned short* __restrict__ Wt2,
                                            unsigned short* __restrict__ xb,
                                            int* __restrict__ cnt,
                                            int* __restrict__ srcC) {
    __shared__ float t[16][17];
    int bid = blockIdx.x;
    if (bid < SCATG) {
        int k = bid * 256 + threadIdx.x;
        if (k >= EP) return;
        int s, d;
        if (k < N_EDGES) { s = ei[k]; d = ei[N_EDGES + k]; }
        else             { s = d = k - N_EDGES; }
        int slot = atomicAdd(&cnt[d], 1);
        if (slot < CAP) srcC[(d << 6) + slot] = s;
    } else if (bid < SCATG + TWG) {
        int t2 = bid - SCATG;                   // 0..511
        const float* W = (t2 < 256) ? W1 : W2;
        unsigned short* Wt = (t2 < 256) ? Wt1 : Wt2;
        int tile = t2 & 255;
        int bx = (tile & 15) * 16, by = (tile >> 4) * 16;   // bx: k-tile, by: n-tile
        int lx = threadIdx.x & 15, ly = threadIdx.x >> 4;
        t[ly][lx] = W[(bx + ly) * D + by + lx];
        __syncthreads();
        Wt[(by + ly) * D + bx + lx] = f2b(t[lx][ly]);       // Wt[n][k]
    } else {
        int i = (bid - SCATG - TWG) * 256 + threadIdx.x;    // float4 index
        float4 v = ((const float4*)x)[i];
        ushort4 o;
        o.x = f2b(v.x); o.y = f2b(v.y); o.z = f2b(v.z); o.w = f2b(v.w);
        ((ushort4*)xb)[i] = o;
    }
}

// ---------------- bf16 MFMA GEMM: 128x128 tile, BK=64, global_load_lds + XOR swizzle -------------
// C[M,256] = A[M,256] @ W ; Wt is [n][k]. Epilogue stores per-colblock es/ed partials (no atomics).

__global__ __launch_bounds__(256) void gemm_bf16(const short* __restrict__ A,
                                                 const short* __restrict__ Wt,
                                                 unsigned short* __restrict__ C,
                                                 const float* __restrict__ avs,
                                                 const float* __restrict__ avd,
                                                 float* __restrict__ esp,
                                                 float* __restrict__ edp) {
    __shared__ short lA[128 * 64];   // 16 KB
    __shared__ short lB[128 * 64];   // 16 KB
    int bid = blockIdx.x;
    int cb, y;
    // XCD swizzle: both col-blocks of a row-band land on the same XCD (bid%8 == y%8)
    if (bid < 768) { int g2 = bid >> 4, r = bid & 15; y = g2 * 8 + (r & 7); cb = r >> 3; }
    else           { int t = bid - 768; y = 384 + (t >> 1); cb = t & 1; }
    int row0 = y << 7;               // 128 rows
    int col0 = cb << 7;              // 128 cols
    int tid = threadIdx.x, wave = tid >> 6, lane = tid & 63;
    int q = lane >> 4, m = lane & 15;
    int lr = lane >> 3;              // staging row within 8-row group
    int kseg = (lane & 7) ^ lr;      // swizzled k-seg this lane fetches

    f32x4 acc[2][8] = {};
    for (int kc = 0; kc < 4; ++kc) {
        if (kc) __syncthreads();
#pragma unroll
        for (int it = 0; it < 4; ++it) {
            int rl = wave * 32 + it * 8;             // local row group base
            int gr = row0 + rl + lr;
            if (gr >= N_NODES) gr = N_NODES - 1;     // clamp; data discarded for rows >= N
            g2lds16(A + (((size_t)gr) << 8) + kc * 64 + kseg * 8, &lA[rl * 64]);
            int gc = col0 + rl + lr;
            g2lds16(Wt + (((size_t)gc) << 8) + kc * 64 + kseg * 8, &lB[rl * 64]);
        }
        __syncthreads();
#pragma unroll
        for (int ks = 0; ks < 2; ++ks) {
            int sw = ((ks * 4 + q) ^ (m & 7)) * 8;
            short8 a0 = *(const short8*)&lA[(wave * 32 + m) * 64 + sw];
            short8 a1 = *(const short8*)&lA[(wave * 32 + 16 + m) * 64 + sw];
#pragma unroll
            for (int ct = 0; ct < 8; ++ct) {
                short8 bf = *(const short8*)&lB[(ct * 16 + m) * 64 + sw];
                acc[0][ct] = __builtin_amdgcn_mfma_f32_16x16x32_bf16(a0, bf, acc[0][ct], 0, 0, 0);
                acc[1][ct] = __builtin_amdgcn_mfma_f32_16x16x32_bf16(a1, bf, acc[1][ct], 0, 0, 0);
            }
        }
    }

    float asv[8], adv[8];
#pragma unroll
    for (int ct = 0; ct < 8; ++ct) {
        asv[ct] = avs[col0 + ct * 16 + m];
        adv[ct] = avd[col0 + ct * 16 + m];
    }
    float* esw = esp + (cb ? N_NODES : 0);
    float* edw = edp + (cb ? N_NODES : 0);
    int rbase = row0 + wave * 32;
#pragma unroll
    for (int rt = 0; rt < 2; ++rt) {
        float ps[4] = {0.f, 0.f, 0.f, 0.f};
        float pd[4] = {0.f, 0.f, 0.f, 0.f};
#pragma unroll
        for (int ct = 0; ct < 8; ++ct)
#pragma unroll
            for (int rr = 0; rr < 4; ++rr) {
                float v = acc[rt][ct][rr];
                int row = rbase + rt * 16 + q * 4 + rr;
                if (row < N_NODES)
                    C[(((size_t)row) << 8) + col0 + ct * 16 + m] = f2b(v);
                ps[rr] += v * asv[ct];
                pd[rr] += v * adv[ct];
            }
#pragma unroll
        for (int rr = 0; rr < 4; ++rr) {
#pragma unroll
            for (int off = 1; off < 16; off <<= 1) {
                ps[rr] += __shfl_xor(ps[rr], off);
                pd[rr] += __shfl_xor(pd[rr], off);
            }
        }
        if (m == 0) {
#pragma unroll
            for (int rr = 0; rr < 4; ++rr) {
                int row = rbase + rt * 16 + q * 4 + rr;
                if (row < N_NODES) {
                    esw[row] = ps[rr];           // plain store: (row,cb) written once
                    edw[row] = pd[rr];
                }
            }
        }
    }
}

// ---------------- edgew: per-edge softmax weight, once per edge, packed {src, w} ----------------

__global__ __launch_bounds__(256) void edgew(const float* __restrict__ esp,
                                             const float* __restrict__ edp,
                                             const int* __restrict__ cntv,
                                             const int* __restrict__ srcC,
                                             int2* __restrict__ pw) {
    int node = blockIdx.x * 4 + (threadIdx.x >> 6);
    int lane = threadIdx.x & 63;
    int c = cntv[node];
    if (c > CAP) c = CAP;
    if (lane >= c) return;
    float edn = edp[node] + edp[N_NODES + node];
    int s = srcC[(node << 6) + lane];
    float e = esp[s] + esp[N_NODES + s] + edn;
    e = e > 0.f ? e : SLOPE * e;
    float w = __expf(fminf(e, 80.f));   // no max-shift: ratios identical, range safe
    pw[(node << 6) + lane] = make_int2(s, __float_as_int(w));
}

// ---------------- slab aggregate: slab = bid%8 -> XCD-resident 3.2MB feature slab ----------------
// Wave handles 2 nodes x 32 features (64B/edge = one cache line). Lane = eg*4+fq:
// eg = edge-in-group (0..15), fq = feature quad (8 feats, 16B).

__global__ __launch_bounds__(256) void aggS(const unsigned short* __restrict__ h,
                                            const int* __restrict__ cntv,
                                            const int2* __restrict__ pw,
                                            const float* __restrict__ bias,
                                            unsigned short* __restrict__ outg) {
    int slab = blockIdx.x & 7;
    int ng = blockIdx.x >> 3;
    int wv = threadIdx.x >> 6, lane = threadIdx.x & 63;
    int eg = lane >> 2, fq = lane & 3;
    int fbase = slab * 32 + fq * 8;      // feature offset (shorts), 16B aligned
    float4 bv0 = *(const float4*)&bias[fbase];
    float4 bv1 = *(const float4*)&bias[fbase + 4];

#pragma unroll
    for (int rep = 0; rep < 2; ++rep) {
        int node = ng * 8 + wv * 2 + rep;
        int c = cntv[node];
        if (c > CAP) c = CAP;
        int2 v = pw[(node << 6) + lane];
        float wl = (lane < c) ? __int_as_float(v.y) : 0.f;
        float den = wl;
        for (int off = 32; off; off >>= 1) den += __shfl_xor(den, off);
        float acc[8] = {};
        for (int base = 0; base < c; base += 16) {
            int e = base + eg;
            float we = __shfl(wl, e);
            int se = __shfl(v.x, e);
            if (e >= c) se = node;       // safe address; we == 0
            uint4 u = *(const uint4*)&h[(((size_t)se) << 8) + fbase];
            acc[0] += we * uas(u.x << 16);
            acc[1] += we * uas(u.x & 0xffff0000u);
            acc[2] += we * uas(u.y << 16);
            acc[3] += we * uas(u.y & 0xffff0000u);
            acc[4] += we * uas(u.z << 16);
            acc[5] += we * uas(u.z & 0xffff0000u);
            acc[6] += we * uas(u.w << 16);
            acc[7] += we * uas(u.w & 0xffff0000u);
        }
        // reduce over eg (lane bits 2..5); butterfly leaves sum in all lanes
#pragma unroll
        for (int off = 4; off < 64; off <<= 1)
#pragma unroll
            for (int i = 0; i < 8; ++i) acc[i] += __shfl_xor(acc[i], off);
        if (eg == 0) {
            float inv = 1.f / den;
            short8 o;
            o[0] = (short)f2b(fmaxf(acc[0] * inv + bv0.x, 0.f));
            o[1] = (short)f2b(fmaxf(acc[1] * inv + bv0.y, 0.f));
            o[2] = (short)f2b(fmaxf(acc[2] * inv + bv0.z, 0.f));
            o[3] = (short)f2b(fmaxf(acc[3] * inv + bv0.w, 0.f));
            o[4] = (short)f2b(fmaxf(acc[4] * inv + bv1.x, 0.f));
            o[5] = (short)f2b(fmaxf(acc[5] * inv + bv1.y, 0.f));
            o[6] = (short)f2b(fmaxf(acc[6] * inv + bv1.z, 0.f));
            o[7] = (short)f2b(fmaxf(acc[7] * inv + bv1.w, 0.f));
            *(short8*)&outg[(((size_t)node) << 8) + fbase] = o;
        }
    }
}

// ---------------- classifier + log_softmax (C=2, bf16 input) ----------------

__global__ __launch_bounds__(256) void classifier(const unsigned short* __restrict__ g,
                                                  const float* __restrict__ Wc,
                                                  const float* __restrict__ bc,
                                                  float* __restrict__ out) {
    int node = blockIdx.x * 4 + (threadIdx.x >> 6);
    int lane = threadIdx.x & 63;
    uint2 u = *(const uint2*)&g[(((size_t)node) << 8) + lane * 4];
    float h0 = uas(u.x << 16), h1 = uas(u.x & 0xffff0000u);
    float h2 = uas(u.y << 16), h3 = uas(u.y & 0xffff0000u);
    float4 w01 = *(const float4*)&Wc[lane * 8];
    float4 w23 = *(const float4*)&Wc[lane * 8 + 4];
    float l0 = h0 * w01.x + h1 * w01.z + h2 * w23.x + h3 * w23.z;
    float l1 = h0 * w01.y + h1 * w01.w + h2 * w23.y + h3 * w23.w;
    for (int off = 32; off; off >>= 1) {
        l0 += __shfl_xor(l0, off);
        l1 += __shfl_xor(l1, off);
    }
    if (lane == 0) {
        l0 += bc[0];
        l1 += bc[1];
        float mx = fmaxf(l0, l1);
        float z = logf(__expf(l0 - mx) + __expf(l1 - mx));
        out[node * 2 + 0] = l0 - mx - z;
        out[node * 2 + 1] = l1 - mx - z;
    }
}

// ---------------- launch ----------------

extern "C" void kernel_launch(void* const* d_in, const int* in_sizes, int n_in,
                              void* d_out, int out_size, void* d_ws, size_t ws_size,
                              hipStream_t stream) {
    const float* x   = (const float*)d_in[0];
    const int*   ei  = (const int*)d_in[1];
    const float* W1  = (const float*)d_in[2];
    const float* a1s = (const float*)d_in[3];
    const float* a1d = (const float*)d_in[4];
    const float* b1  = (const float*)d_in[5];
    const float* W2  = (const float*)d_in[6];
    const float* a2s = (const float*)d_in[7];
    const float* a2d = (const float*)d_in[8];
    const float* b2  = (const float*)d_in[9];
    const float* Wc  = (const float*)d_in[10];
    const float* bc  = (const float*)d_in[11];
    float* out = (float*)d_out;

    char* p = (char*)d_ws;
    unsigned short* xb  = (unsigned short*)p; p += (size_t)N_NODES * D * 2;  // x bf16; reused as g2
    unsigned short* h   = (unsigned short*)p; p += (size_t)N_NODES * D * 2;  // gemm out
    unsigned short* g   = (unsigned short*)p; p += (size_t)N_NODES * D * 2;  // agg1 out
    unsigned short* Wt1 = (unsigned short*)p; p += (size_t)D * D * 2;
    unsigned short* Wt2 = (unsigned short*)p; p += (size_t)D * D * 2;
    int*  srcC = (int*)p;  p += (size_t)N_NODES * CAP * 4;     // 12.8 MB buckets
    int2* pw   = (int2*)p; p += (size_t)N_NODES * CAP * 8;     // 25.6 MB packed {src,w}
    float* esp = (float*)p; p += (size_t)2 * N_NODES * 4;      // per-colblock partials
    float* edp = (float*)p; p += (size_t)2 * N_NODES * 4;
    int*  cnt  = (int*)p;  p += (size_t)N_NODES * 4;

    hipMemsetAsync(cnt, 0, (size_t)N_NODES * 4, stream);

    dim3 b256(256);

    prep<<<SCATG + TWG + CASTG, b256, 0, stream>>>(ei, W1, W2, x, Wt1, Wt2, xb, cnt, srcC);

    // layer 1
    gemm_bf16<<<782, b256, 0, stream>>>((const short*)xb, (const short*)Wt1, h,
                                        a1s, a1d, esp, edp);
    edgew<<<12500, b256, 0, stream>>>(esp, edp, cnt, srcC, pw);
    aggS<<<50000, b256, 0, stream>>>(h, cnt, pw, b1, g);
    // layer 2
    gemm_bf16<<<782, b256, 0, stream>>>((const short*)g, (const short*)Wt2, h,
                                        a2s, a2d, esp, edp);
    edgew<<<12500, b256, 0, stream>>>(esp, edp, cnt, srcC, pw);
    aggS<<<50000, b256, 0, stream>>>(h, cnt, pw, b2, xb);
    // classifier
    classifier<<<12500, b256, 0, stream>>>(xb, Wc, bc, out);
}

// Round 10
// 339.920 us; speedup vs baseline: 1.7528x; 1.7528x over previous
//
#include <hip/hip_runtime.h>
#include <math.h>

#define N_NODES 50000
#define N_EDGES 800000
#define EP (N_EDGES + N_NODES)   // 850000 edges incl. self-loops
#define D 256
#define SLOPE 0.2f
#define CAP 64                   // per-dst bucket capacity; max degree ~45 << 64
#define TWG 512                  // transW blocks
#define CASTG 12500              // x-cast blocks (N*D/4 float4s / 256)
#define SCATG 3321               // scatter blocks = ceil(EP/256)
#define GEMMB 782                // gemm blocks (2 col x 391 row)

typedef __attribute__((ext_vector_type(8))) short short8;
typedef __attribute__((ext_vector_type(4))) float f32x4;
typedef const __attribute__((address_space(1))) unsigned int* as1_u32;
typedef __attribute__((address_space(3))) unsigned int* as3_u32;

__device__ __forceinline__ unsigned short f2b(float f) {
    unsigned u = __float_as_uint(f);
    unsigned r = (u + 0x7FFFu + ((u >> 16) & 1u)) >> 16;   // RNE
    return (unsigned short)r;
}
__device__ __forceinline__ float uas(unsigned u) { return __uint_as_float(u); }
__device__ __forceinline__ void g2lds16(const void* g, void* l) {
    __builtin_amdgcn_global_load_lds((as1_u32)g, (as3_u32)l, 16, 0, 0);
}

// ---------------- prep0: weight transposes + x cast (pure BW, ~15us) ----------------

__global__ __launch_bounds__(256) void prep0(const float* __restrict__ W1,
                                             const float* __restrict__ W2,
                                             const float* __restrict__ x,
                                             unsigned short* __restrict__ Wt1,
                                             unsigned short* __restrict__ Wt2,
                                             unsigned short* __restrict__ xb) {
    __shared__ float t[16][17];
    int bid = blockIdx.x;
    if (bid < TWG) {
        const float* W = (bid < 256) ? W1 : W2;
        unsigned short* Wt = (bid < 256) ? Wt1 : Wt2;
        int tile = bid & 255;
        int bx = (tile & 15) * 16, by = (tile >> 4) * 16;   // bx: k-tile, by: n-tile
        int lx = threadIdx.x & 15, ly = threadIdx.x >> 4;
        t[ly][lx] = W[(bx + ly) * D + by + lx];
        __syncthreads();
        Wt[(by + ly) * D + bx + lx] = f2b(t[lx][ly]);       // Wt[n][k]
    } else {
        int i = (bid - TWG) * 256 + threadIdx.x;            // float4 index
        float4 v = ((const float4*)x)[i];
        ushort4 o;
        o.x = f2b(v.x); o.y = f2b(v.y); o.z = f2b(v.z); o.w = f2b(v.w);
        ((ushort4*)xb)[i] = o;
    }
}

// ---------------- bf16 MFMA GEMM (m97-style) + optional fused bucket scatter -------------
// Blocks < GEMMB: C[M,256] = A[M,256] @ W (Wt is [n][k]); fused es/ed epilogue (atomicAdd).
// Blocks >= GEMMB (SCAT=1, layer 1 only): latency-bound edge scatter co-scheduled with MFMA.
// LDS: [row][64 k-shorts], seg s at row r holds kseg = s ^ (r&7) (global_load_lds forbids pad).

template<int SCAT>
__global__ __launch_bounds__(256) void gemm_bf16(const short* __restrict__ A,
                                                 const short* __restrict__ Wt,
                                                 unsigned short* __restrict__ C,
                                                 const float* __restrict__ avs,
                                                 const float* __restrict__ avd,
                                                 float* __restrict__ es,
                                                 float* __restrict__ ed,
                                                 const int* __restrict__ ei,
                                                 int* __restrict__ cnt,
                                                 int* __restrict__ srcC) {
    int bid = blockIdx.x;
    if (SCAT && bid >= GEMMB) {
        int k = (bid - GEMMB) * 256 + threadIdx.x;
        if (k >= EP) return;
        int s, d;
        if (k < N_EDGES) { s = ei[k]; d = ei[N_EDGES + k]; }
        else             { s = d = k - N_EDGES; }
        int slot = atomicAdd(&cnt[d], 1);
        if (slot < CAP) srcC[(d << 6) + slot] = s;
        return;
    }
    __shared__ short lA[128 * 64];   // 16 KB
    __shared__ short lB[128 * 64];   // 16 KB
    int cb, y;
    // XCD swizzle: both col-blocks of a row-band land on the same XCD (bid%8 == y%8)
    if (bid < 768) { int g2 = bid >> 4, r = bid & 15; y = g2 * 8 + (r & 7); cb = r >> 3; }
    else           { int t = bid - 768; y = 384 + (t >> 1); cb = t & 1; }
    int row0 = y << 7;               // 128 rows
    int col0 = cb << 7;              // 128 cols
    int tid = threadIdx.x, wave = tid >> 6, lane = tid & 63;
    int q = lane >> 4, m = lane & 15;
    int lr = lane >> 3;              // staging row within 8-row group
    int kseg = (lane & 7) ^ lr;      // swizzled k-seg this lane fetches

    f32x4 acc[2][8] = {};
    for (int kc = 0; kc < 4; ++kc) {
        if (kc) __syncthreads();
#pragma unroll
        for (int it = 0; it < 4; ++it) {
            int rl = wave * 32 + it * 8;             // local row group base
            int gr = row0 + rl + lr;
            if (gr >= N_NODES) gr = N_NODES - 1;     // clamp; data discarded for rows >= N
            g2lds16(A + (((size_t)gr) << 8) + kc * 64 + kseg * 8, &lA[rl * 64]);
            int gc = col0 + rl + lr;
            g2lds16(Wt + (((size_t)gc) << 8) + kc * 64 + kseg * 8, &lB[rl * 64]);
        }
        __syncthreads();
#pragma unroll
        for (int ks = 0; ks < 2; ++ks) {
            int sw = ((ks * 4 + q) ^ (m & 7)) * 8;
            short8 a0 = *(const short8*)&lA[(wave * 32 + m) * 64 + sw];
            short8 a1 = *(const short8*)&lA[(wave * 32 + 16 + m) * 64 + sw];
#pragma unroll
            for (int ct = 0; ct < 8; ++ct) {
                short8 bf = *(const short8*)&lB[(ct * 16 + m) * 64 + sw];
                acc[0][ct] = __builtin_amdgcn_mfma_f32_16x16x32_bf16(a0, bf, acc[0][ct], 0, 0, 0);
                acc[1][ct] = __builtin_amdgcn_mfma_f32_16x16x32_bf16(a1, bf, acc[1][ct], 0, 0, 0);
            }
        }
    }

    float asv[8], adv[8];
#pragma unroll
    for (int ct = 0; ct < 8; ++ct) {
        asv[ct] = avs[col0 + ct * 16 + m];
        adv[ct] = avd[col0 + ct * 16 + m];
    }
    int rbase = row0 + wave * 32;
#pragma unroll
    for (int rt = 0; rt < 2; ++rt) {
        float ps[4] = {0.f, 0.f, 0.f, 0.f};
        float pd[4] = {0.f, 0.f, 0.f, 0.f};
#pragma unroll
        for (int ct = 0; ct < 8; ++ct)
#pragma unroll
            for (int rr = 0; rr < 4; ++rr) {
                float v = acc[rt][ct][rr];
                int row = rbase + rt * 16 + q * 4 + rr;
                if (row < N_NODES)
                    C[(((size_t)row) << 8) + col0 + ct * 16 + m] = f2b(v);
                ps[rr] += v * asv[ct];
                pd[rr] += v * adv[ct];
            }
#pragma unroll
        for (int rr = 0; rr < 4; ++rr) {
#pragma unroll
            for (int off = 1; off < 16; off <<= 1) {
                ps[rr] += __shfl_xor(ps[rr], off);
                pd[rr] += __shfl_xor(pd[rr], off);
            }
        }
        if (m == 0) {
#pragma unroll
            for (int rr = 0; rr < 4; ++rr) {
                int row = rbase + rt * 16 + q * 4 + rr;
                if (row < N_NODES) {
                    atomicAdd(&es[row], ps[rr]);
                    atomicAdd(&ed[row], pd[rr]);
                }
            }
        }
    }
}

// ---------------- fused logit + softmax + aggregate (+classifier), wave/node, bucket CSR ----------------
// Lanes 0-31 = feats lane32*8..+8 of edge j, lanes 32-63 same feats of edge j+1;
// one dwordx4 gather serves 2 edges; shfl_xor(32) merges halves.

template<int CLS>
__global__ __launch_bounds__(256) void aggregate(const unsigned short* __restrict__ h,
                                                 const float* __restrict__ es,
                                                 const float* __restrict__ ed,
                                                 const int* __restrict__ cntv,
                                                 const int* __restrict__ srcC,
                                                 const float* __restrict__ bias,
                                                 unsigned short* __restrict__ outg,
                                                 const float* __restrict__ Wc,
                                                 const float* __restrict__ bc,
                                                 float* __restrict__ out) {
    __shared__ float wbuf[4][64];
    __shared__ int   sbuf[4][64];
    int wv = threadIdx.x >> 6;
    int node = blockIdx.x * 4 + wv;
    if (node >= N_NODES) return;
    int lane = threadIdx.x & 63;
    int lane32 = lane & 31, half = lane >> 5;
    size_t fo = (size_t)lane32 * 8;      // feature offset in shorts (16B)
    int cnt = cntv[node];
    if (cnt > CAP) cnt = CAP;
    float edn = ed[node];

    // phase 1: one lane per edge computes w once
    int s = node;                        // safe index for invalid lanes (w=0)
    float w = 0.f;
    if (lane < cnt) {
        s = srcC[(node << 6) + lane];
        float e = es[s] + edn;
        e = e > 0.f ? e : SLOPE * e;
        w = __expf(fminf(e, 80.f));      // no max-shift: ratios identical, range safe
    }
    wbuf[wv][lane] = w;
    sbuf[wv][lane] = s;
    float den = w;
    float accf[8] = {};

    // phase 2: 2 edges per gather instruction
#pragma unroll 8
    for (int jj = 0; jj < cnt; jj += 2) {
        int idx = jj + half;             // may hit cnt when odd: w=0 there, safe
        float wj = wbuf[wv][idx];
        int sj = sbuf[wv][idx];
        uint4 u = *(const uint4*)&h[(((size_t)sj) << 8) + fo];
        accf[0] += wj * uas(u.x << 16);
        accf[1] += wj * uas(u.x & 0xffff0000u);
        accf[2] += wj * uas(u.y << 16);
        accf[3] += wj * uas(u.y & 0xffff0000u);
        accf[4] += wj * uas(u.z << 16);
        accf[5] += wj * uas(u.z & 0xffff0000u);
        accf[6] += wj * uas(u.w << 16);
        accf[7] += wj * uas(u.w & 0xffff0000u);
    }
    for (int off = 32; off; off >>= 1) den += __shfl_xor(den, off);
#pragma unroll
    for (int i = 0; i < 8; ++i) accf[i] += __shfl_xor(accf[i], 32);

    float inv = 1.f / den;
    float4 b0 = *(const float4*)&bias[fo];
    float4 b1 = *(const float4*)&bias[fo + 4];
    float r[8];
    r[0] = fmaxf(accf[0] * inv + b0.x, 0.f);
    r[1] = fmaxf(accf[1] * inv + b0.y, 0.f);
    r[2] = fmaxf(accf[2] * inv + b0.z, 0.f);
    r[3] = fmaxf(accf[3] * inv + b0.w, 0.f);
    r[4] = fmaxf(accf[4] * inv + b1.x, 0.f);
    r[5] = fmaxf(accf[5] * inv + b1.y, 0.f);
    r[6] = fmaxf(accf[6] * inv + b1.z, 0.f);
    r[7] = fmaxf(accf[7] * inv + b1.w, 0.f);

    if (!CLS) {
        if (half == 0) {
            short8 o;
#pragma unroll
            for (int i = 0; i < 8; ++i) o[i] = (short)f2b(r[i]);
            *(short8*)&outg[(((size_t)node) << 8) + fo] = o;
        }
    } else {
        float l0 = 0.f, l1 = 0.f;
#pragma unroll
        for (int f2 = 0; f2 < 4; ++f2) {
            float4 wc = *(const float4*)&Wc[fo * 2 + f2 * 4];
            l0 += r[f2 * 2] * wc.x + r[f2 * 2 + 1] * wc.z;
            l1 += r[f2 * 2] * wc.y + r[f2 * 2 + 1] * wc.w;
        }
#pragma unroll
        for (int off = 1; off < 32; off <<= 1) {
            l0 += __shfl_xor(l0, off);
            l1 += __shfl_xor(l1, off);
        }
        if (lane == 0) {
            l0 += bc[0];
            l1 += bc[1];
            float mx = fmaxf(l0, l1);
            float z = logf(__expf(l0 - mx) + __expf(l1 - mx));
            out[node * 2 + 0] = l0 - mx - z;
            out[node * 2 + 1] = l1 - mx - z;
        }
    }
}

// ---------------- launch ----------------

extern "C" void kernel_launch(void* const* d_in, const int* in_sizes, int n_in,
                              void* d_out, int out_size, void* d_ws, size_t ws_size,
                              hipStream_t stream) {
    const float* x   = (const float*)d_in[0];
    const int*   ei  = (const int*)d_in[1];
    const float* W1  = (const float*)d_in[2];
    const float* a1s = (const float*)d_in[3];
    const float* a1d = (const float*)d_in[4];
    const float* b1  = (const float*)d_in[5];
    const float* W2  = (const float*)d_in[6];
    const float* a2s = (const float*)d_in[7];
    const float* a2d = (const float*)d_in[8];
    const float* b2  = (const float*)d_in[9];
    const float* Wc  = (const float*)d_in[10];
    const float* bc  = (const float*)d_in[11];
    float* out = (float*)d_out;

    char* p = (char*)d_ws;
    unsigned short* xb  = (unsigned short*)p; p += (size_t)N_NODES * D * 2;  // x bf16; reused as agg1 out
    unsigned short* h   = (unsigned short*)p; p += (size_t)N_NODES * D * 2;  // gemm out
    unsigned short* g   = (unsigned short*)p; p += (size_t)N_NODES * D * 2;  // agg1 out
    unsigned short* Wt1 = (unsigned short*)p; p += (size_t)D * D * 2;
    unsigned short* Wt2 = (unsigned short*)p; p += (size_t)D * D * 2;
    int* srcC = (int*)p;    p += (size_t)N_NODES * CAP * 4;      // 12.8 MB buckets
    // zeroed region: cnt, es1, ed1, es2, ed2 (contiguous)
    int*   cnt = (int*)p;   p += (size_t)N_NODES * 4;
    float* es1 = (float*)p; p += (size_t)N_NODES * 4;
    float* ed1 = (float*)p; p += (size_t)N_NODES * 4;
    float* es2 = (float*)p; p += (size_t)N_NODES * 4;
    float* ed2 = (float*)p; p += (size_t)N_NODES * 4;

    hipMemsetAsync(cnt, 0, (size_t)5 * N_NODES * 4, stream);

    dim3 b256(256);
    int ngrid = (N_NODES + 3) / 4;

    prep0<<<TWG + CASTG, b256, 0, stream>>>(W1, W2, x, Wt1, Wt2, xb);

    // layer 1: MFMA blocks + latency-bound scatter blocks co-scheduled in one dispatch
    gemm_bf16<1><<<GEMMB + SCATG, b256, 0, stream>>>((const short*)xb, (const short*)Wt1, h,
                                                     a1s, a1d, es1, ed1, ei, cnt, srcC);
    aggregate<0><<<ngrid, b256, 0, stream>>>(h, es1, ed1, cnt, srcC, b1, g,
                                             nullptr, nullptr, nullptr);
    // layer 2
    gemm_bf16<0><<<GEMMB, b256, 0, stream>>>((const short*)g, (const short*)Wt2, h,
                                             a2s, a2d, es2, ed2, nullptr, nullptr, nullptr);
    aggregate<1><<<ngrid, b256, 0, stream>>>(h, es2, ed2, cnt, srcC, b2, nullptr,
                                             Wc, bc, out);
}

// Round 11
// 308.603 us; speedup vs baseline: 1.9307x; 1.1015x over previous
//
#include <hip/hip_runtime.h>
#include <math.h>

#define N_NODES 50000
#define N_EDGES 800000
#define EP (N_EDGES + N_NODES)   // 850000 edges incl. self-loops
#define D 256
#define SLOPE 0.2f
#define NBIN 196                 // coarse bins = dst>>8
#define BINB 6144                // bin capacity (avg 4337, +28 sigma)
#define SORTA 208                // sortA blocks x 4096 edges
#define SAE 4096
#define TWG 512                  // transW blocks
#define CASTG 12500              // x-cast blocks
#define GEMMB 782

typedef __attribute__((ext_vector_type(8))) short short8;
typedef __attribute__((ext_vector_type(4))) float f32x4;
typedef const __attribute__((address_space(1))) unsigned int* as1_u32;
typedef __attribute__((address_space(3))) unsigned int* as3_u32;

__device__ __forceinline__ unsigned short f2b(float f) {
    unsigned u = __float_as_uint(f);
    unsigned r = (u + 0x7FFFu + ((u >> 16) & 1u)) >> 16;   // RNE
    return (unsigned short)r;
}
__device__ __forceinline__ float uas(unsigned u) { return __uint_as_float(u); }
__device__ __forceinline__ void g2lds16(const void* g, void* l) {
    __builtin_amdgcn_global_load_lds((as1_u32)g, (as3_u32)l, 16, 0, 0);
}

// ------ prep0: sortA (coarse edge binning, runs first) + transW + x cast, one dispatch ------

__global__ __launch_bounds__(256) void prep0(const int* __restrict__ ei,
                                             const float* __restrict__ W1,
                                             const float* __restrict__ W2,
                                             const float* __restrict__ x,
                                             unsigned short* __restrict__ Wt1,
                                             unsigned short* __restrict__ Wt2,
                                             unsigned short* __restrict__ xb,
                                             int* __restrict__ binCnt,
                                             int* __restrict__ coarse) {
    __shared__ float t[16][17];
    __shared__ int hist[NBIN], base[NBIN], lrk[NBIN];
    int bid = blockIdx.x;
    if (bid < SORTA) {
        int e0 = bid * SAE;
        for (int i = threadIdx.x; i < NBIN; i += 256) { hist[i] = 0; lrk[i] = 0; }
        __syncthreads();
        for (int i = threadIdx.x; i < SAE; i += 256) {
            int k = e0 + i;
            if (k >= EP) break;
            int d = (k < N_EDGES) ? ei[N_EDGES + k] : (k - N_EDGES);
            atomicAdd(&hist[d >> 8], 1);
        }
        __syncthreads();
        for (int i = threadIdx.x; i < NBIN; i += 256)
            if (hist[i]) base[i] = atomicAdd(&binCnt[i], hist[i]);
        __syncthreads();
        for (int i = threadIdx.x; i < SAE; i += 256) {
            int k = e0 + i;
            if (k >= EP) break;
            int s, d;
            if (k < N_EDGES) { s = ei[k]; d = ei[N_EDGES + k]; }
            else             { s = d = k - N_EDGES; }
            int b = d >> 8;
            int r = base[b] + atomicAdd(&lrk[b], 1);
            if (r < BINB) coarse[b * BINB + r] = s | ((d & 255) << 16);   // s < 2^16
        }
    } else if (bid < SORTA + TWG) {
        int t2 = bid - SORTA;                   // 0..511
        const float* W = (t2 < 256) ? W1 : W2;
        unsigned short* Wt = (t2 < 256) ? Wt1 : Wt2;
        int tile = t2 & 255;
        int bx = (tile & 15) * 16, by = (tile >> 4) * 16;
        int lx = threadIdx.x & 15, ly = threadIdx.x >> 4;
        t[ly][lx] = W[(bx + ly) * D + by + lx];
        __syncthreads();
        Wt[(by + ly) * D + bx + lx] = f2b(t[lx][ly]);       // Wt[n][k]
    } else {
        int i = (bid - SORTA - TWG) * 256 + threadIdx.x;    // float4 index, exact fit
        float4 v = ((const float4*)x)[i];
        ushort4 o;
        o.x = f2b(v.x); o.y = f2b(v.y); o.z = f2b(v.z); o.w = f2b(v.w);
        ((ushort4*)xb)[i] = o;
    }
}

// ------ sortB: per-bin dst-sort in LDS (LDS atomics only) -> CSR srcC + {start,count} ------

__global__ __launch_bounds__(1024) void sortB(const int* __restrict__ coarse,
                                              const int* __restrict__ binCnt,
                                              int* __restrict__ srcC,
                                              int2* __restrict__ rpc) {
    __shared__ int h[256], off[256], h2[256];
    __shared__ int ssrc[BINB];
    int bin = blockIdx.x, tid = threadIdx.x;
    int cnt = binCnt[bin];
    if (cnt > BINB) cnt = BINB;
    if (tid < 256) { h[tid] = 0; h2[tid] = 0; }
    __syncthreads();
    int vv[6]; int nv = 0;
#pragma unroll
    for (int it = 0; it < 6; ++it) {
        int i = it * 1024 + tid;
        if (i < cnt) {
            int v = coarse[bin * BINB + i];
            vv[nv++] = v;
            atomicAdd(&h[v >> 16], 1);
        }
    }
    __syncthreads();
    if (tid < 256) off[tid] = h[tid];
    __syncthreads();
    for (int o = 1; o < 256; o <<= 1) {
        int tv = (tid < 256 && tid >= o) ? off[tid - o] : 0;
        __syncthreads();
        if (tid < 256) off[tid] += tv;     // inclusive scan; exclusive = off - h
        __syncthreads();
    }
    for (int j = 0; j < nv; ++j) {
        int ld = vv[j] >> 16;
        int pos = off[ld] - h[ld] + atomicAdd(&h2[ld], 1);
        ssrc[pos] = vv[j] & 0xffff;
    }
    __syncthreads();
#pragma unroll
    for (int it = 0; it < 6; ++it) {
        int i = it * 1024 + tid;
        if (i < cnt) srcC[bin * BINB + i] = ssrc[i];
    }
    int node = bin * 256 + tid;
    if (tid < 256 && node < N_NODES)
        rpc[node] = make_int2(bin * BINB + off[tid] - h[tid], h[tid]);
}

// ------ bf16 MFMA GEMM: 128x128, BK=64, global_load_lds + XOR swizzle, LDS-repacked C ------
// C[M,256] = A[M,256] @ W ; Wt is [n][k]. es/ed partials per col-block: plain stores.

__global__ __launch_bounds__(256) void gemm_bf16(const short* __restrict__ A,
                                                 const short* __restrict__ Wt,
                                                 unsigned short* __restrict__ C,
                                                 const float* __restrict__ avs,
                                                 const float* __restrict__ avd,
                                                 float* __restrict__ esp,
                                                 float* __restrict__ edp) {
    __shared__ short sbuf[128 * 132];   // 33.8 KB; aliased: lA/lB (staging), then repack buffer
    short* lA = sbuf;
    short* lB = sbuf + 128 * 64;
    int bid = blockIdx.x;
    int cb, y;
    // XCD swizzle: both col-blocks of a row-band land on the same XCD
    if (bid < 768) { int g2 = bid >> 4, r = bid & 15; y = g2 * 8 + (r & 7); cb = r >> 3; }
    else           { int t = bid - 768; y = 384 + (t >> 1); cb = t & 1; }
    int row0 = y << 7;
    int col0 = cb << 7;
    int tid = threadIdx.x, wave = tid >> 6, lane = tid & 63;
    int q = lane >> 4, m = lane & 15;
    int lr = lane >> 3;
    int kseg = (lane & 7) ^ lr;

    f32x4 acc[2][8] = {};
    for (int kc = 0; kc < 4; ++kc) {
        if (kc) __syncthreads();
#pragma unroll
        for (int it = 0; it < 4; ++it) {
            int rl = wave * 32 + it * 8;
            int gr = row0 + rl + lr;
            if (gr >= N_NODES) gr = N_NODES - 1;     // clamp; rows never stored
            g2lds16(A + (((size_t)gr) << 8) + kc * 64 + kseg * 8, &lA[rl * 64]);
            int gc = col0 + rl + lr;
            g2lds16(Wt + (((size_t)gc) << 8) + kc * 64 + kseg * 8, &lB[rl * 64]);
        }
        __syncthreads();
#pragma unroll
        for (int ks = 0; ks < 2; ++ks) {
            int sw = ((ks * 4 + q) ^ (m & 7)) * 8;
            short8 a0 = *(const short8*)&lA[(wave * 32 + m) * 64 + sw];
            short8 a1 = *(const short8*)&lA[(wave * 32 + 16 + m) * 64 + sw];
#pragma unroll
            for (int ct = 0; ct < 8; ++ct) {
                short8 bf = *(const short8*)&lB[(ct * 16 + m) * 64 + sw];
                acc[0][ct] = __builtin_amdgcn_mfma_f32_16x16x32_bf16(a0, bf, acc[0][ct], 0, 0, 0);
                acc[1][ct] = __builtin_amdgcn_mfma_f32_16x16x32_bf16(a1, bf, acc[1][ct], 0, 0, 0);
            }
        }
    }

    // fused es/ed partials (fp32 acc, quad-shuffle reduce, plain store per (row, cb))
    float asv[8], adv[8];
#pragma unroll
    for (int ct = 0; ct < 8; ++ct) {
        asv[ct] = avs[col0 + ct * 16 + m];
        adv[ct] = avd[col0 + ct * 16 + m];
    }
    float* esw = esp + (cb ? N_NODES : 0);
    float* edw = edp + (cb ? N_NODES : 0);
    int rbase = row0 + wave * 32;
#pragma unroll
    for (int rt = 0; rt < 2; ++rt) {
        float ps[4] = {0.f, 0.f, 0.f, 0.f};
        float pd[4] = {0.f, 0.f, 0.f, 0.f};
#pragma unroll
        for (int ct = 0; ct < 8; ++ct)
#pragma unroll
            for (int rr = 0; rr < 4; ++rr) {
                float v = acc[rt][ct][rr];
                ps[rr] += v * asv[ct];
                pd[rr] += v * adv[ct];
            }
#pragma unroll
        for (int rr = 0; rr < 4; ++rr) {
#pragma unroll
            for (int off = 1; off < 16; off <<= 1) {
                ps[rr] += __shfl_xor(ps[rr], off);
                pd[rr] += __shfl_xor(pd[rr], off);
            }
        }
        if (m == 0) {
#pragma unroll
            for (int rr = 0; rr < 4; ++rr) {
                int row = rbase + rt * 16 + q * 4 + rr;
                if (row < N_NODES) {
                    esw[row] = ps[rr];
                    edw[row] = pd[rr];
                }
            }
        }
    }

    // repack C tile through LDS (stride 132) -> coalesced short8 stores
    __syncthreads();
#pragma unroll
    for (int rt = 0; rt < 2; ++rt)
#pragma unroll
        for (int ct = 0; ct < 8; ++ct)
#pragma unroll
            for (int rr = 0; rr < 4; ++rr) {
                int lrow = wave * 32 + rt * 16 + q * 4 + rr;
                sbuf[lrow * 132 + ct * 16 + m] = (short)f2b(acc[rt][ct][rr]);
            }
    __syncthreads();
#pragma unroll
    for (int it = 0; it < 8; ++it) {
        int idx = it * 256 + tid;            // 0..2047
        int lrow = idx >> 4, cg = idx & 15;
        int row = row0 + lrow;
        if (row < N_NODES)
            *(short8*)&C[(((size_t)row) << 8) + col0 + cg * 8] = *(const short8*)&sbuf[lrow * 132 + cg * 8];
    }
}

// ------ fused logit + softmax + aggregate (+classifier), wave/node, sorted CSR ------

template<int CLS>
__global__ __launch_bounds__(256) void aggregate(const unsigned short* __restrict__ h,
                                                 const float* __restrict__ esp,
                                                 const float* __restrict__ edp,
                                                 const int2* __restrict__ rpc,
                                                 const int* __restrict__ srcC,
                                                 const float* __restrict__ bias,
                                                 unsigned short* __restrict__ outg,
                                                 const float* __restrict__ Wc,
                                                 const float* __restrict__ bc,
                                                 float* __restrict__ out) {
    __shared__ float wbuf[4][64];
    __shared__ int   sbuf[4][64];
    int wv = threadIdx.x >> 6;
    int node = blockIdx.x * 4 + wv;
    if (node >= N_NODES) return;
    int lane = threadIdx.x & 63;
    int lane32 = lane & 31, half = lane >> 5;
    size_t fo = (size_t)lane32 * 8;
    int2 rc = rpc[node];
    int start = rc.x;
    int cnt = rc.y > 64 ? 64 : rc.y;
    float edn = edp[node] + edp[N_NODES + node];

    int s = node;
    float w = 0.f;
    if (lane < cnt) {
        s = srcC[start + lane];
        float e = esp[s] + esp[N_NODES + s] + edn;
        e = e > 0.f ? e : SLOPE * e;
        w = __expf(fminf(e, 80.f));      // no max-shift: ratios identical, range safe
    }
    wbuf[wv][lane] = w;
    sbuf[wv][lane] = s;
    float den = w;
    float accf[8] = {};

#pragma unroll 8
    for (int jj = 0; jj < cnt; jj += 2) {
        int idx = jj + half;
        float wj = wbuf[wv][idx];
        int sj = sbuf[wv][idx];
        uint4 u = *(const uint4*)&h[(((size_t)sj) << 8) + fo];
        accf[0] += wj * uas(u.x << 16);
        accf[1] += wj * uas(u.x & 0xffff0000u);
        accf[2] += wj * uas(u.y << 16);
        accf[3] += wj * uas(u.y & 0xffff0000u);
        accf[4] += wj * uas(u.z << 16);
        accf[5] += wj * uas(u.z & 0xffff0000u);
        accf[6] += wj * uas(u.w << 16);
        accf[7] += wj * uas(u.w & 0xffff0000u);
    }
    for (int off = 32; off; off >>= 1) den += __shfl_xor(den, off);
#pragma unroll
    for (int i = 0; i < 8; ++i) accf[i] += __shfl_xor(accf[i], 32);

    float inv = 1.f / den;
    float4 b0 = *(const float4*)&bias[fo];
    float4 b1 = *(const float4*)&bias[fo + 4];
    float r[8];
    r[0] = fmaxf(accf[0] * inv + b0.x, 0.f);
    r[1] = fmaxf(accf[1] * inv + b0.y, 0.f);
    r[2] = fmaxf(accf[2] * inv + b0.z, 0.f);
    r[3] = fmaxf(accf[3] * inv + b0.w, 0.f);
    r[4] = fmaxf(accf[4] * inv + b1.x, 0.f);
    r[5] = fmaxf(accf[5] * inv + b1.y, 0.f);
    r[6] = fmaxf(accf[6] * inv + b1.z, 0.f);
    r[7] = fmaxf(accf[7] * inv + b1.w, 0.f);

    if (!CLS) {
        if (half == 0) {
            short8 o;
#pragma unroll
            for (int i = 0; i < 8; ++i) o[i] = (short)f2b(r[i]);
            *(short8*)&outg[(((size_t)node) << 8) + fo] = o;
        }
    } else {
        float l0 = 0.f, l1 = 0.f;
#pragma unroll
        for (int f2 = 0; f2 < 4; ++f2) {
            float4 wc = *(const float4*)&Wc[fo * 2 + f2 * 4];
            l0 += r[f2 * 2] * wc.x + r[f2 * 2 + 1] * wc.z;
            l1 += r[f2 * 2] * wc.y + r[f2 * 2 + 1] * wc.w;
        }
#pragma unroll
        for (int off = 1; off < 32; off <<= 1) {
            l0 += __shfl_xor(l0, off);
            l1 += __shfl_xor(l1, off);
        }
        if (lane == 0) {
            l0 += bc[0];
            l1 += bc[1];
            float mx = fmaxf(l0, l1);
            float z = logf(__expf(l0 - mx) + __expf(l1 - mx));
            out[node * 2 + 0] = l0 - mx - z;
            out[node * 2 + 1] = l1 - mx - z;
        }
    }
}

// ---------------- launch ----------------

extern "C" void kernel_launch(void* const* d_in, const int* in_sizes, int n_in,
                              void* d_out, int out_size, void* d_ws, size_t ws_size,
                              hipStream_t stream) {
    const float* x   = (const float*)d_in[0];
    const int*   ei  = (const int*)d_in[1];
    const float* W1  = (const float*)d_in[2];
    const float* a1s = (const float*)d_in[3];
    const float* a1d = (const float*)d_in[4];
    const float* b1  = (const float*)d_in[5];
    const float* W2  = (const float*)d_in[6];
    const float* a2s = (const float*)d_in[7];
    const float* a2d = (const float*)d_in[8];
    const float* b2  = (const float*)d_in[9];
    const float* Wc  = (const float*)d_in[10];
    const float* bc  = (const float*)d_in[11];
    float* out = (float*)d_out;

    char* p = (char*)d_ws;
    unsigned short* xb  = (unsigned short*)p; p += (size_t)N_NODES * D * 2;  // x bf16; reused as agg1 out g
    unsigned short* h   = (unsigned short*)p; p += (size_t)N_NODES * D * 2;  // gemm out
    unsigned short* g   = (unsigned short*)p; p += (size_t)N_NODES * D * 2;  // agg1 out
    unsigned short* Wt1 = (unsigned short*)p; p += (size_t)D * D * 2;
    unsigned short* Wt2 = (unsigned short*)p; p += (size_t)D * D * 2;
    int*  coarse = (int*)p;  p += (size_t)NBIN * BINB * 4;    // 4.8 MB packed (s | ld<<16)
    int*  srcC   = (int*)p;  p += (size_t)NBIN * BINB * 4;    // 4.8 MB dst-sorted src
    int2* rpc    = (int2*)p; p += (size_t)N_NODES * 8;        // {start, count} per node
    float* esp   = (float*)p; p += (size_t)2 * N_NODES * 4;   // per-colblock partials
    float* edp   = (float*)p; p += (size_t)2 * N_NODES * 4;
    int*  binCnt = (int*)p;  p += (size_t)NBIN * 4;

    hipMemsetAsync(binCnt, 0, (size_t)NBIN * 4, stream);

    dim3 b256(256);
    int ngrid = (N_NODES + 3) / 4;

    prep0<<<SORTA + TWG + CASTG, b256, 0, stream>>>(ei, W1, W2, x, Wt1, Wt2, xb, binCnt, coarse);
    sortB<<<NBIN, 1024, 0, stream>>>(coarse, binCnt, srcC, rpc);

    // layer 1
    gemm_bf16<<<GEMMB, b256, 0, stream>>>((const short*)xb, (const short*)Wt1, h,
                                          a1s, a1d, esp, edp);
    aggregate<0><<<ngrid, b256, 0, stream>>>(h, esp, edp, rpc, srcC, b1, g,
                                             nullptr, nullptr, nullptr);
    // layer 2
    gemm_bf16<<<GEMMB, b256, 0, stream>>>((const short*)g, (const short*)Wt2, h,
                                          a2s, a2d, esp, edp);
    aggregate<1><<<ngrid, b256, 0, stream>>>(h, esp, edp, rpc, srcC, b2, nullptr,
                                             Wc, bc, out);
}

// Round 12
// 296.429 us; speedup vs baseline: 2.0100x; 1.0411x over previous
//
#include <hip/hip_runtime.h>
#include <math.h>

#define N_NODES 50000
#define N_EDGES 800000
#define EP (N_EDGES + N_NODES)   // 850000 edges incl. self-loops
#define D 256
#define SLOPE 0.2f
#define NBIN 196                 // coarse bins = dst>>8
#define BINB 6144                // bin capacity (avg 4337, +27 sigma)
#define SORTA 208                // sortA blocks x 4096 edges
#define SAE 4096
#define TWG 512                  // transW blocks
#define CASTG 12500              // x-cast blocks
#define GEMMB 782
#define CAP 64

typedef __attribute__((ext_vector_type(8))) short short8;
typedef __attribute__((ext_vector_type(4))) float f32x4;
typedef const __attribute__((address_space(1))) unsigned int* as1_u32;
typedef __attribute__((address_space(3))) unsigned int* as3_u32;

__device__ __forceinline__ unsigned short f2b(float f) {
    unsigned u = __float_as_uint(f);
    unsigned r = (u + 0x7FFFu + ((u >> 16) & 1u)) >> 16;   // RNE
    return (unsigned short)r;
}
__device__ __forceinline__ float uas(unsigned u) { return __uint_as_float(u); }
__device__ __forceinline__ void g2lds16(const void* g, void* l) {
    __builtin_amdgcn_global_load_lds((as1_u32)g, (as3_u32)l, 16, 0, 0);
}

// ------ prep0: sortA (coarse edge binning) + transW + x cast, one dispatch ------

__global__ __launch_bounds__(256) void prep0(const int* __restrict__ ei,
                                             const float* __restrict__ W1,
                                             const float* __restrict__ W2,
                                             const float* __restrict__ x,
                                             unsigned short* __restrict__ Wt1,
                                             unsigned short* __restrict__ Wt2,
                                             unsigned short* __restrict__ xb,
                                             int* __restrict__ binCnt,
                                             int* __restrict__ coarse) {
    __shared__ float t[16][17];
    __shared__ int hist[NBIN], base[NBIN], lrk[NBIN];
    int bid = blockIdx.x;
    if (bid < SORTA) {
        int e0 = bid * SAE;
        for (int i = threadIdx.x; i < NBIN; i += 256) { hist[i] = 0; lrk[i] = 0; }
        __syncthreads();
        for (int i = threadIdx.x; i < SAE; i += 256) {
            int k = e0 + i;
            if (k >= EP) break;
            int d = (k < N_EDGES) ? ei[N_EDGES + k] : (k - N_EDGES);
            atomicAdd(&hist[d >> 8], 1);
        }
        __syncthreads();
        for (int i = threadIdx.x; i < NBIN; i += 256)
            if (hist[i]) base[i] = atomicAdd(&binCnt[i], hist[i]);
        __syncthreads();
        for (int i = threadIdx.x; i < SAE; i += 256) {
            int k = e0 + i;
            if (k >= EP) break;
            int s, d;
            if (k < N_EDGES) { s = ei[k]; d = ei[N_EDGES + k]; }
            else             { s = d = k - N_EDGES; }
            int b = d >> 8;
            int r = base[b] + atomicAdd(&lrk[b], 1);
            if (r < BINB) coarse[b * BINB + r] = s | ((d & 255) << 16);   // s < 2^16
        }
    } else if (bid < SORTA + TWG) {
        int t2 = bid - SORTA;
        const float* W = (t2 < 256) ? W1 : W2;
        unsigned short* Wt = (t2 < 256) ? Wt1 : Wt2;
        int tile = t2 & 255;
        int bx = (tile & 15) * 16, by = (tile >> 4) * 16;
        int lx = threadIdx.x & 15, ly = threadIdx.x >> 4;
        t[ly][lx] = W[(bx + ly) * D + by + lx];
        __syncthreads();
        Wt[(by + ly) * D + bx + lx] = f2b(t[lx][ly]);       // Wt[n][k]
    } else {
        int i = (bid - SORTA - TWG) * 256 + threadIdx.x;    // float4 index, exact fit
        float4 v = ((const float4*)x)[i];
        ushort4 o;
        o.x = f2b(v.x); o.y = f2b(v.y); o.z = f2b(v.z); o.w = f2b(v.w);
        ((ushort4*)xb)[i] = o;
    }
}

// ------ bf16 MFMA GEMM (m97-style) + optional fused sortB tail blocks ------
// Blocks < GEMMB: C[M,256]=A@W, Wt [n][k]; es/ed per-colblock partials via plain stores;
// C repacked through LDS for coalesced short8 stores.
// Blocks >= GEMMB (SORT=1): per-bin LDS-rank scatter into aligned node<<6 buckets.

template<int SORT>
__global__ __launch_bounds__(256) void gemm_bf16(const short* __restrict__ A,
                                                 const short* __restrict__ Wt,
                                                 unsigned short* __restrict__ C,
                                                 const float* __restrict__ avs,
                                                 const float* __restrict__ avd,
                                                 float* __restrict__ esp,
                                                 float* __restrict__ edp,
                                                 const int* __restrict__ coarse,
                                                 const int* __restrict__ binCnt,
                                                 int* __restrict__ srcC,
                                                 int* __restrict__ cntN) {
    __shared__ short sbuf[128 * 132];   // staging (lA/lB) then C-repack
    __shared__ int h2[256];
    int bid = blockIdx.x;
    if (SORT && bid >= GEMMB) {
        int bin = bid - GEMMB;
        int tid = threadIdx.x;
        h2[tid] = 0;
        int cb2 = binCnt[bin];
        if (cb2 > BINB) cb2 = BINB;
        __syncthreads();
        for (int i = tid; i < cb2; i += 256) {
            int v = coarse[bin * BINB + i];
            int ld = v >> 16;
            int pos = atomicAdd(&h2[ld], 1);
            if (pos < CAP) srcC[((bin * 256 + ld) << 6) + pos] = v & 0xffff;
        }
        __syncthreads();
        int node = bin * 256 + tid;
        if (node < N_NODES) cntN[node] = h2[tid];
        return;
    }
    short* lA = sbuf;
    short* lB = sbuf + 128 * 64;
    int cb, y;
    // XCD swizzle: both col-blocks of a row-band land on the same XCD
    if (bid < 768) { int g2 = bid >> 4, r = bid & 15; y = g2 * 8 + (r & 7); cb = r >> 3; }
    else           { int t = bid - 768; y = 384 + (t >> 1); cb = t & 1; }
    int row0 = y << 7;
    int col0 = cb << 7;
    int tid = threadIdx.x, wave = tid >> 6, lane = tid & 63;
    int q = lane >> 4, m = lane & 15;
    int lr = lane >> 3;
    int kseg = (lane & 7) ^ lr;

    f32x4 acc[2][8] = {};
    for (int kc = 0; kc < 4; ++kc) {
        if (kc) __syncthreads();
#pragma unroll
        for (int it = 0; it < 4; ++it) {
            int rl = wave * 32 + it * 8;
            int gr = row0 + rl + lr;
            if (gr >= N_NODES) gr = N_NODES - 1;     // clamp; rows never stored
            g2lds16(A + (((size_t)gr) << 8) + kc * 64 + kseg * 8, &lA[rl * 64]);
            int gc = col0 + rl + lr;
            g2lds16(Wt + (((size_t)gc) << 8) + kc * 64 + kseg * 8, &lB[rl * 64]);
        }
        __syncthreads();
#pragma unroll
        for (int ks = 0; ks < 2; ++ks) {
            int sw = ((ks * 4 + q) ^ (m & 7)) * 8;
            short8 a0 = *(const short8*)&lA[(wave * 32 + m) * 64 + sw];
            short8 a1 = *(const short8*)&lA[(wave * 32 + 16 + m) * 64 + sw];
#pragma unroll
            for (int ct = 0; ct < 8; ++ct) {
                short8 bf = *(const short8*)&lB[(ct * 16 + m) * 64 + sw];
                acc[0][ct] = __builtin_amdgcn_mfma_f32_16x16x32_bf16(a0, bf, acc[0][ct], 0, 0, 0);
                acc[1][ct] = __builtin_amdgcn_mfma_f32_16x16x32_bf16(a1, bf, acc[1][ct], 0, 0, 0);
            }
        }
    }

    float asv[8], adv[8];
#pragma unroll
    for (int ct = 0; ct < 8; ++ct) {
        asv[ct] = avs[col0 + ct * 16 + m];
        adv[ct] = avd[col0 + ct * 16 + m];
    }
    float* esw = esp + (cb ? N_NODES : 0);
    float* edw = edp + (cb ? N_NODES : 0);
    int rbase = row0 + wave * 32;
#pragma unroll
    for (int rt = 0; rt < 2; ++rt) {
        float ps[4] = {0.f, 0.f, 0.f, 0.f};
        float pd[4] = {0.f, 0.f, 0.f, 0.f};
#pragma unroll
        for (int ct = 0; ct < 8; ++ct)
#pragma unroll
            for (int rr = 0; rr < 4; ++rr) {
                float v = acc[rt][ct][rr];
                ps[rr] += v * asv[ct];
                pd[rr] += v * adv[ct];
            }
#pragma unroll
        for (int rr = 0; rr < 4; ++rr) {
#pragma unroll
            for (int off = 1; off < 16; off <<= 1) {
                ps[rr] += __shfl_xor(ps[rr], off);
                pd[rr] += __shfl_xor(pd[rr], off);
            }
        }
        if (m == 0) {
#pragma unroll
            for (int rr = 0; rr < 4; ++rr) {
                int row = rbase + rt * 16 + q * 4 + rr;
                if (row < N_NODES) {
                    esw[row] = ps[rr];
                    edw[row] = pd[rr];
                }
            }
        }
    }

    // repack C tile through LDS (stride 132) -> coalesced short8 stores
    __syncthreads();
#pragma unroll
    for (int rt = 0; rt < 2; ++rt)
#pragma unroll
        for (int ct = 0; ct < 8; ++ct)
#pragma unroll
            for (int rr = 0; rr < 4; ++rr) {
                int lrow = wave * 32 + rt * 16 + q * 4 + rr;
                sbuf[lrow * 132 + ct * 16 + m] = (short)f2b(acc[rt][ct][rr]);
            }
    __syncthreads();
#pragma unroll
    for (int it = 0; it < 8; ++it) {
        int idx = it * 256 + tid;
        int lrow = idx >> 4, cg = idx & 15;
        int row = row0 + lrow;
        if (row < N_NODES)
            *(short8*)&C[(((size_t)row) << 8) + col0 + cg * 8] = *(const short8*)&sbuf[lrow * 132 + cg * 8];
    }
}

// ------ fused logit + softmax + aggregate (+classifier), wave/node, aligned buckets ------
// Lanes 0-31 = feats lane32*8..+8 of edge j, lanes 32-63 same feats of edge j+1.

template<int CLS>
__global__ __launch_bounds__(256) void aggregate(const unsigned short* __restrict__ h,
                                                 const float* __restrict__ esp,
                                                 const float* __restrict__ edp,
                                                 const int* __restrict__ cntv,
                                                 const int* __restrict__ srcC,
                                                 const float* __restrict__ bias,
                                                 unsigned short* __restrict__ outg,
                                                 const float* __restrict__ Wc,
                                                 const float* __restrict__ bc,
                                                 float* __restrict__ out) {
    __shared__ float wbuf[4][64];
    __shared__ int   sbuf[4][64];
    int wv = threadIdx.x >> 6;
    int node = blockIdx.x * 4 + wv;
    if (node >= N_NODES) return;
    int lane = threadIdx.x & 63;
    int lane32 = lane & 31, half = lane >> 5;
    size_t fo = (size_t)lane32 * 8;      // feature offset in shorts (16B)
    int cnt = cntv[node];
    if (cnt > CAP) cnt = CAP;
    float edn = edp[node] + edp[N_NODES + node];

    // phase 1: one lane per edge computes w once
    int s = node;
    float w = 0.f;
    if (lane < cnt) {
        s = srcC[(node << 6) + lane];
        float e = esp[s] + esp[N_NODES + s] + edn;
        e = e > 0.f ? e : SLOPE * e;
        w = __expf(fminf(e, 80.f));      // no max-shift: ratios identical, range safe
    }
    wbuf[wv][lane] = w;
    sbuf[wv][lane] = s;
    float den = w;
    float accf[8] = {};

    // phase 2: 2 edges per gather instruction
#pragma unroll 8
    for (int jj = 0; jj < cnt; jj += 2) {
        int idx = jj + half;
        float wj = wbuf[wv][idx];
        int sj = sbuf[wv][idx];
        uint4 u = *(const uint4*)&h[(((size_t)sj) << 8) + fo];
        accf[0] += wj * uas(u.x << 16);
        accf[1] += wj * uas(u.x & 0xffff0000u);
        accf[2] += wj * uas(u.y << 16);
        accf[3] += wj * uas(u.y & 0xffff0000u);
        accf[4] += wj * uas(u.z << 16);
        accf[5] += wj * uas(u.z & 0xffff0000u);
        accf[6] += wj * uas(u.w << 16);
        accf[7] += wj * uas(u.w & 0xffff0000u);
    }
    for (int off = 32; off; off >>= 1) den += __shfl_xor(den, off);
#pragma unroll
    for (int i = 0; i < 8; ++i) accf[i] += __shfl_xor(accf[i], 32);

    float inv = 1.f / den;
    float4 b0 = *(const float4*)&bias[fo];
    float4 b1 = *(const float4*)&bias[fo + 4];
    float r[8];
    r[0] = fmaxf(accf[0] * inv + b0.x, 0.f);
    r[1] = fmaxf(accf[1] * inv + b0.y, 0.f);
    r[2] = fmaxf(accf[2] * inv + b0.z, 0.f);
    r[3] = fmaxf(accf[3] * inv + b0.w, 0.f);
    r[4] = fmaxf(accf[4] * inv + b1.x, 0.f);
    r[5] = fmaxf(accf[5] * inv + b1.y, 0.f);
    r[6] = fmaxf(accf[6] * inv + b1.z, 0.f);
    r[7] = fmaxf(accf[7] * inv + b1.w, 0.f);

    if (!CLS) {
        if (half == 0) {
            short8 o;
#pragma unroll
            for (int i = 0; i < 8; ++i) o[i] = (short)f2b(r[i]);
            *(short8*)&outg[(((size_t)node) << 8) + fo] = o;
        }
    } else {
        float l0 = 0.f, l1 = 0.f;
#pragma unroll
        for (int f2 = 0; f2 < 4; ++f2) {
            float4 wc = *(const float4*)&Wc[fo * 2 + f2 * 4];
            l0 += r[f2 * 2] * wc.x + r[f2 * 2 + 1] * wc.z;
            l1 += r[f2 * 2] * wc.y + r[f2 * 2 + 1] * wc.w;
        }
#pragma unroll
        for (int off = 1; off < 32; off <<= 1) {
            l0 += __shfl_xor(l0, off);
            l1 += __shfl_xor(l1, off);
        }
        if (lane == 0) {
            l0 += bc[0];
            l1 += bc[1];
            float mx = fmaxf(l0, l1);
            float z = logf(__expf(l0 - mx) + __expf(l1 - mx));
            out[node * 2 + 0] = l0 - mx - z;
            out[node * 2 + 1] = l1 - mx - z;
        }
    }
}

// ---------------- launch ----------------

extern "C" void kernel_launch(void* const* d_in, const int* in_sizes, int n_in,
                              void* d_out, int out_size, void* d_ws, size_t ws_size,
                              hipStream_t stream) {
    const float* x   = (const float*)d_in[0];
    const int*   ei  = (const int*)d_in[1];
    const float* W1  = (const float*)d_in[2];
    const float* a1s = (const float*)d_in[3];
    const float* a1d = (const float*)d_in[4];
    const float* b1  = (const float*)d_in[5];
    const float* W2  = (const float*)d_in[6];
    const float* a2s = (const float*)d_in[7];
    const float* a2d = (const float*)d_in[8];
    const float* b2  = (const float*)d_in[9];
    const float* Wc  = (const float*)d_in[10];
    const float* bc  = (const float*)d_in[11];
    float* out = (float*)d_out;

    char* p = (char*)d_ws;
    unsigned short* xb  = (unsigned short*)p; p += (size_t)N_NODES * D * 2;  // x bf16 / g2
    unsigned short* h   = (unsigned short*)p; p += (size_t)N_NODES * D * 2;  // gemm out
    unsigned short* g   = (unsigned short*)p; p += (size_t)N_NODES * D * 2;  // agg1 out
    unsigned short* Wt1 = (unsigned short*)p; p += (size_t)D * D * 2;
    unsigned short* Wt2 = (unsigned short*)p; p += (size_t)D * D * 2;
    int*  coarse = (int*)p;  p += (size_t)NBIN * BINB * 4;    // 4.8 MB packed (s | ld<<16)
    int*  srcC   = (int*)p;  p += (size_t)N_NODES * CAP * 4;  // 12.8 MB aligned buckets
    int*  cntN   = (int*)p;  p += (size_t)N_NODES * 4;
    float* esp   = (float*)p; p += (size_t)2 * N_NODES * 4;   // per-colblock partials
    float* edp   = (float*)p; p += (size_t)2 * N_NODES * 4;
    int*  binCnt = (int*)p;  p += (size_t)NBIN * 4;

    hipMemsetAsync(binCnt, 0, (size_t)NBIN * 4, stream);

    dim3 b256(256);
    int ngrid = (N_NODES + 3) / 4;

    prep0<<<SORTA + TWG + CASTG, b256, 0, stream>>>(ei, W1, W2, x, Wt1, Wt2, xb, binCnt, coarse);

    // layer 1: gemm + fused sortB tail blocks
    gemm_bf16<1><<<GEMMB + NBIN, b256, 0, stream>>>((const short*)xb, (const short*)Wt1, h,
                                                    a1s, a1d, esp, edp,
                                                    coarse, binCnt, srcC, cntN);
    aggregate<0><<<ngrid, b256, 0, stream>>>(h, esp, edp, cntN, srcC, b1, g,
                                             nullptr, nullptr, nullptr);
    // layer 2
    gemm_bf16<0><<<GEMMB, b256, 0, stream>>>((const short*)g, (const short*)Wt2, h,
                                             a2s, a2d, esp, edp,
                                             nullptr, nullptr, nullptr, nullptr);
    aggregate<1><<<ngrid, b256, 0, stream>>>(h, esp, edp, cntN, srcC, b2, nullptr,
                                             Wc, bc, out);
}